// Round 2
// baseline (273.733 us; speedup 1.0000x reference)
//
#include <hip/hip_runtime.h>

// BahdanauAttention_16518444220431 — diagonal-DP recurrence on MI355X (gfx950).
// R2: up/down chains run CONCURRENTLY (waves 0-3 up, waves 4-7 down) halving
// serial depth 16->8; final GEMM does two K-loops (W4*up + W4*down) instead of
// bf16 fusion; HW __bf16 casts replace manual RNE pack; W2 VGPR cache cut to
// 4 ks to fit 128 VGPRs at 4 waves/SIMD (2 blocks/CU, LDS 2x67KB).

typedef __bf16 bf16x8 __attribute__((ext_vector_type(8)));
typedef __bf16 bf16x4 __attribute__((ext_vector_type(4)));
typedef float f32x16 __attribute__((ext_vector_type(16)));

#define MFMA32(a, b, c) __builtin_amdgcn_mfma_f32_32x32x16_bf16(a, b, c, 0, 0, 0)

__device__ __forceinline__ unsigned short f2bf(float f) {
  unsigned int u = __builtin_bit_cast(unsigned int, f);
  u += 0x7fffu + ((u >> 16) & 1u);
  return (unsigned short)(u >> 16);
}

// ws layout (bf16 elements):
//   [0,65536)        W2 fragments: ((ot*16+ks)*64+lane)*8+j ; o=ot*32+(lane&31), k=ks*16+(lane>>5)*8+j
//   [65536,131072)   W4 fragments, same permutation
//   [131072,135168)  W1-extra frags: lanes<32: j<4 -> W1[o][j], j==4 -> b1[o]+b2[o], else 0
//   [135168,139264)  W3-extra frags: j==4 -> b3[o]+2*b4[o]
__global__ void prep_kernel(const float* __restrict__ W1, const float* __restrict__ b1,
                            const float* __restrict__ W2, const float* __restrict__ b2,
                            const float* __restrict__ W3, const float* __restrict__ b3,
                            const float* __restrict__ W4, const float* __restrict__ b4,
                            unsigned short* __restrict__ ws) {
  int idx = blockIdx.x * 256 + threadIdx.x;
  if (idx >= 139264) return;
  float v = 0.0f;
  if (idx < 131072) {
    const float* W = (idx < 65536) ? W2 : W4;
    int i = idx & 65535;
    int j = i & 7, f = i >> 3;
    int lane = f & 63, slot = f >> 6;
    int ks = slot & 15, ot = slot >> 4;
    int o = ot * 32 + (lane & 31);
    int k = ks * 16 + (lane >> 5) * 8 + j;
    v = W[o * 256 + k];
  } else {
    int i = idx - 131072;
    bool first = (i < 4096);
    int ii = i & 4095;
    int j = ii & 7, f = ii >> 3;
    int lane = f & 63, ot = f >> 6;
    int o = ot * 32 + (lane & 31);
    if (lane < 32) {
      if (j < 4) v = first ? W1[o * 4 + j] : W3[o * 4 + j];
      else if (j == 4) v = first ? (b1[o] + b2[o]) : (b3[o] + 2.0f * b4[o]);
    }
  }
  ws[idx] = f2bf(v);
}

__global__ __launch_bounds__(512, 4)
void chain_kernel(const float* __restrict__ x, const unsigned short* __restrict__ ws,
                  float* __restrict__ out) {
  // U buffers: 64 rows x 32 16B-chunks (256 bf16/row), chunk XOR-swizzled by (row&7)
  __shared__ int4 Ubuf[2][64 * 32];
  __shared__ int4 xw[80];   // [x0,x1,x2,x3,1,0,0,0] bf16 chunks for rows j0-8 .. j0+71
  __shared__ int4 zc;       // zero chunk for hi-lane extra-K reads

  const int tid = threadIdx.x;
  const int l = tid & 63;
  const int w = tid >> 6;        // 0..7
  const int phase = w >> 2;      // 0 = up chain, 1 = down chain
  const int ot0 = (w & 3) * 2;   // two 32-wide o-tiles per wave
  const int lane31 = l & 31;
  const int khalf = l >> 5;
  const int b = blockIdx.x >> 5;
  const int j0 = (blockIdx.x & 31) * 64;

  const int4* w2f = (const int4*)ws;
  const int4* w4f = (const int4*)(ws + 65536);
  const int4* w1xg = (const int4*)(ws + 131072);
  const int4* w3xg = (const int4*)(ws + 135168);

  if (tid == 0) zc = make_int4(0, 0, 0, 0);
  if (tid < 80) {
    int j = j0 - 8 + tid;
    int4 c = make_int4(0, 0, 0, 0);
    if (j >= 0 && j < 2048) {
      const float* xb = x + (b * 4) * 2048 + j;
      unsigned short h0 = f2bf(xb[0]);
      unsigned short h1 = f2bf(xb[2048]);
      unsigned short h2 = f2bf(xb[4096]);
      unsigned short h3 = f2bf(xb[6144]);
      c = make_int4((int)(h0 | ((unsigned int)h1 << 16)),
                    (int)(h2 | ((unsigned int)h3 << 16)),
                    0x00003f80, 0);  // chunk[4] = bf16(1.0) multiplies the bias row
    }
    xw[tid] = c;
  }

  // Per-wave cached fragments: W1-extra (both phases use W1/W2) + 4 ks of W2.
  bf16x8 w2c[2][4];
  bf16x8 w1x[2];
#pragma unroll
  for (int t2 = 0; t2 < 2; ++t2) {
    w1x[t2] = __builtin_bit_cast(bf16x8, w1xg[(ot0 + t2) * 64 + l]);
#pragma unroll
    for (int ks = 0; ks < 4; ++ks)
      w2c[t2][ks] = __builtin_bit_cast(bf16x8, w2f[((ot0 + t2) * 16 + ks) * 64 + l]);
  }
  __syncthreads();

  const int mrow0 = lane31;
  const int mrow1 = 32 + lane31;
  int4* U = Ubuf[phase];

#pragma unroll 1
  for (int t = 1; t <= 8; ++t) {
    f32x16 acc[2][2] = {};
    // ---- extra K=16 step: adds a[idx] + bias (zero chunk at seq boundaries) ----
#pragma unroll
    for (int mt = 0; mt < 2; ++mt) {
      int m = mt ? mrow1 : mrow0;
      int widx = (phase == 0) ? (m + t - 1) : (m + 17 - t);
      const int4* p = (l < 32) ? (xw + widx) : (&zc);
      bf16x8 bx = __builtin_bit_cast(bf16x8, *p);
      acc[mt][0] = MFMA32(w1x[0], bx, acc[mt][0]);
      acc[mt][1] = MFMA32(w1x[1], bx, acc[mt][1]);
    }
    // ---- main GEMM over previous state (skip at t=1: state is zero) ----
    if (t > 1) {
#pragma unroll
      for (int ks = 0; ks < 16; ++ks) {
        int c0 = 2 * ks + khalf;
        bf16x8 bu0 = __builtin_bit_cast(bf16x8, U[mrow0 * 32 + (c0 ^ (mrow0 & 7))]);
        bf16x8 bu1 = __builtin_bit_cast(bf16x8, U[mrow1 * 32 + (c0 ^ (mrow1 & 7))]);
        bf16x8 af0, af1;
        if (ks < 4) { af0 = w2c[0][ks]; af1 = w2c[1][ks]; }
        else {
          af0 = __builtin_bit_cast(bf16x8, w2f[(ot0 * 16 + ks) * 64 + l]);
          af1 = __builtin_bit_cast(bf16x8, w2f[((ot0 + 1) * 16 + ks) * 64 + l]);
        }
        acc[0][0] = MFMA32(af0, bu0, acc[0][0]);
        acc[0][1] = MFMA32(af1, bu0, acc[0][1]);
        acc[1][0] = MFMA32(af0, bu1, acc[1][0]);
        acc[1][1] = MFMA32(af1, bu1, acc[1][1]);
      }
    }
    __syncthreads();
    // ---- relu + HW bf16 pack + swizzled writeback (C layout: col=m, row=o) ----
#pragma unroll
    for (int mt = 0; mt < 2; ++mt) {
      int row = mt ? mrow1 : mrow0;
#pragma unroll
      for (int t2 = 0; t2 < 2; ++t2) {
        int ot = ot0 + t2;
#pragma unroll
        for (int q = 0; q < 4; ++q) {
          bf16x4 h;
          h.x = (__bf16)fmaxf(acc[mt][t2][4 * q + 0], 0.0f);
          h.y = (__bf16)fmaxf(acc[mt][t2][4 * q + 1], 0.0f);
          h.z = (__bf16)fmaxf(acc[mt][t2][4 * q + 2], 0.0f);
          h.w = (__bf16)fmaxf(acc[mt][t2][4 * q + 3], 0.0f);
          int co = ot * 4 + q;
          int coff = row * 32 + (co ^ (row & 7));
          *(uint2*)((char*)(U + coff) + khalf * 8) = __builtin_bit_cast(uint2, h);
        }
      }
    }
    __syncthreads();
  }

  // ---- final: miu^T = relu(W3x + b3 + 2b4 + W4*shift_r(up) + W4*shift_l(down)) ----
  // Sliding window left Ubuf[0] row m = up_8[j0+m-1], Ubuf[1] row m = down_8[j0+m+1].
  {
    const int mrow = phase * 32 + lane31;  // waves 0-3: rows 0-31; waves 4-7: rows 32-63
    f32x16 acc[2] = {};
    bf16x8 w3x0 = __builtin_bit_cast(bf16x8, w3xg[ot0 * 64 + l]);
    bf16x8 w3x1 = __builtin_bit_cast(bf16x8, w3xg[(ot0 + 1) * 64 + l]);
    {
      const int4* p = (l < 32) ? (xw + mrow + 8) : (&zc);
      bf16x8 bx = __builtin_bit_cast(bf16x8, *p);
      acc[0] = MFMA32(w3x0, bx, acc[0]);
      acc[1] = MFMA32(w3x1, bx, acc[1]);
    }
#pragma unroll 1
    for (int ph2 = 0; ph2 < 2; ++ph2) {
      const int4* S = Ubuf[ph2];
#pragma unroll
      for (int ks = 0; ks < 16; ++ks) {
        int c0 = 2 * ks + khalf;
        bf16x8 bu = __builtin_bit_cast(bf16x8, S[mrow * 32 + (c0 ^ (mrow & 7))]);
        bf16x8 af0 = __builtin_bit_cast(bf16x8, w4f[(ot0 * 16 + ks) * 64 + l]);
        bf16x8 af1 = __builtin_bit_cast(bf16x8, w4f[((ot0 + 1) * 16 + ks) * 64 + l]);
        acc[0] = MFMA32(af0, bu, acc[0]);
        acc[1] = MFMA32(af1, bu, acc[1]);
      }
    }
    int pbase = (b * 2048 + j0 + mrow) * 256;
#pragma unroll
    for (int t2 = 0; t2 < 2; ++t2) {
#pragma unroll
      for (int q = 0; q < 4; ++q) {
        int ob = (ot0 + t2) * 32 + 8 * q + 4 * khalf;
        float4 v;
        v.x = fmaxf(acc[t2][4 * q + 0], 0.0f);
        v.y = fmaxf(acc[t2][4 * q + 1], 0.0f);
        v.z = fmaxf(acc[t2][4 * q + 2], 0.0f);
        v.w = fmaxf(acc[t2][4 * q + 3], 0.0f);
        *(float4*)(out + pbase + ob) = v;
      }
    }
  }
}

extern "C" void kernel_launch(void* const* d_in, const int* in_sizes, int n_in,
                              void* d_out, int out_size, void* d_ws, size_t ws_size,
                              hipStream_t stream) {
  const float* x  = (const float*)d_in[0];
  const float* W1 = (const float*)d_in[1];
  const float* b1 = (const float*)d_in[2];
  const float* W2 = (const float*)d_in[3];
  const float* b2 = (const float*)d_in[4];
  const float* W3 = (const float*)d_in[5];
  const float* b3 = (const float*)d_in[6];
  const float* W4 = (const float*)d_in[7];
  const float* b4 = (const float*)d_in[8];
  unsigned short* ws = (unsigned short*)d_ws;

  prep_kernel<<<544, 256, 0, stream>>>(W1, b1, W2, b2, W3, b3, W4, b4, ws);
  chain_kernel<<<512, 512, 0, stream>>>(x, ws, (float*)d_out);
}

// Round 3
// 254.464 us; speedup vs baseline: 1.0757x; 1.0757x over previous
//
#include <hip/hip_runtime.h>

// BahdanauAttention_16518444220431 — diagonal-DP recurrence on MI355X (gfx950).
// R3: two-kernel split. Kernel A: 1024 blocks (512 up + 512 down chains in
// parallel), 8 serial steps each, ONE 32KB U-buffer -> 4 blocks/CU; final
// shifted state dumped to d_ws (layout verbatim = swizzled chunks).
// Kernel B: 512 blocks, final GEMM relu(W3x+b3+2b4 + W4*sup + W4*sdown).
// 256-thread blocks ONLY (R2's 512-thread variant spilled: VGPR 64, +600MB HBM).

typedef __bf16 bf16x8 __attribute__((ext_vector_type(8)));
typedef __bf16 bf16x4 __attribute__((ext_vector_type(4)));
typedef float f32x16 __attribute__((ext_vector_type(16)));

#define MFMA32(a, b, c) __builtin_amdgcn_mfma_f32_32x32x16_bf16(a, b, c, 0, 0, 0)

__device__ __forceinline__ unsigned short f2bf(float f) {
  unsigned int u = __builtin_bit_cast(unsigned int, f);
  u += 0x7fffu + ((u >> 16) & 1u);
  return (unsigned short)(u >> 16);
}

// ws layout (bf16 elements):
//   [0,65536)        W2 fragments: ((ot*16+ks)*64+lane)*8+j ; o=ot*32+(lane&31), k=ks*16+(lane>>5)*8+j
//   [65536,131072)   W4 fragments, same permutation
//   [131072,135168)  W1-extra frags: lanes<32: j<4 -> W1[o][j], j==4 -> b1[o]+b2[o], else 0
//   [135168,139264)  W3-extra frags: j==4 -> b3[o]+2*b4[o]
//   [139264, +2*512*32768)  chain states: [chain][tile512][2048 int4] (swizzled chunk layout)
#define STATE_OFF 139264

__global__ void prep_kernel(const float* __restrict__ W1, const float* __restrict__ b1,
                            const float* __restrict__ W2, const float* __restrict__ b2,
                            const float* __restrict__ W3, const float* __restrict__ b3,
                            const float* __restrict__ W4, const float* __restrict__ b4,
                            unsigned short* __restrict__ ws) {
  int idx = blockIdx.x * 256 + threadIdx.x;
  if (idx >= 139264) return;
  float v = 0.0f;
  if (idx < 131072) {
    const float* W = (idx < 65536) ? W2 : W4;
    int i = idx & 65535;
    int j = i & 7, f = i >> 3;
    int lane = f & 63, slot = f >> 6;
    int ks = slot & 15, ot = slot >> 4;
    int o = ot * 32 + (lane & 31);
    int k = ks * 16 + (lane >> 5) * 8 + j;
    v = W[o * 256 + k];
  } else {
    int i = idx - 131072;
    bool first = (i < 4096);
    int ii = i & 4095;
    int j = ii & 7, f = ii >> 3;
    int lane = f & 63, ot = f >> 6;
    int o = ot * 32 + (lane & 31);
    if (lane < 32) {
      if (j < 4) v = first ? W1[o * 4 + j] : W3[o * 4 + j];
      else if (j == 4) v = first ? (b1[o] + b2[o]) : (b3[o] + 2.0f * b4[o]);
    }
  }
  ws[idx] = f2bf(v);
}

__global__ __launch_bounds__(256, 4)
void chain_kernel(const float* __restrict__ x, unsigned short* __restrict__ ws) {
  // U: 64 rows x 32 16B-chunks (256 bf16/row), chunk XOR-swizzled by (row&7)
  __shared__ int4 U[64 * 32];
  __shared__ int4 xw[80];   // [x0,x1,x2,x3,1,0,0,0] bf16 chunks for rows j0-8 .. j0+71
  __shared__ int4 zc;

  const int tid = threadIdx.x;
  const int l = tid & 63;
  const int w = tid >> 6;
  const int lane31 = l & 31;
  const int khalf = l >> 5;
  const int phase = blockIdx.x >> 9;           // 0 = up, 1 = down
  const int tile = blockIdx.x & 511;
  const int b = tile >> 5;
  const int j0 = (tile & 31) * 64;

  const int4* w2f = (const int4*)ws;
  const int4* w1xg = (const int4*)(ws + 131072);

  if (tid == 0) zc = make_int4(0, 0, 0, 0);
  if (tid < 80) {
    int j = j0 - 8 + tid;
    int4 c = make_int4(0, 0, 0, 0);
    if (j >= 0 && j < 2048) {
      const float* xb = x + (b * 4) * 2048 + j;
      unsigned short h0 = f2bf(xb[0]);
      unsigned short h1 = f2bf(xb[2048]);
      unsigned short h2 = f2bf(xb[4096]);
      unsigned short h3 = f2bf(xb[6144]);
      c = make_int4((int)(h0 | ((unsigned int)h1 << 16)),
                    (int)(h2 | ((unsigned int)h3 << 16)),
                    0x00003f80, 0);  // chunk[4] = bf16(1.0) multiplies the bias row
    }
    xw[tid] = c;
  }

  const int ot0 = w * 2;
  bf16x8 w2c[2][8];
  bf16x8 w1x[2];
#pragma unroll
  for (int t2 = 0; t2 < 2; ++t2) {
    w1x[t2] = __builtin_bit_cast(bf16x8, w1xg[(ot0 + t2) * 64 + l]);
#pragma unroll
    for (int ks = 0; ks < 8; ++ks)
      w2c[t2][ks] = __builtin_bit_cast(bf16x8, w2f[((ot0 + t2) * 16 + ks) * 64 + l]);
  }
  __syncthreads();

  const int mrow0 = lane31;
  const int mrow1 = 32 + lane31;

#pragma unroll 1
  for (int t = 1; t <= 8; ++t) {
    f32x16 acc[2][2] = {};
    // ---- extra K=16 step: adds a[pos] + bias (zero chunk beyond seq edges) ----
#pragma unroll
    for (int mt = 0; mt < 2; ++mt) {
      int m = mt ? mrow1 : mrow0;
      int widx = (phase == 0) ? (m + t - 1) : (m + 17 - t);
      const int4* p = (l < 32) ? (xw + widx) : (&zc);
      bf16x8 bx = __builtin_bit_cast(bf16x8, *p);
      acc[mt][0] = MFMA32(w1x[0], bx, acc[mt][0]);
      acc[mt][1] = MFMA32(w1x[1], bx, acc[mt][1]);
    }
    // ---- main GEMM over previous state (skip at t=1: state is zero) ----
    if (t > 1) {
#pragma unroll
      for (int ks = 0; ks < 16; ++ks) {
        int c0 = 2 * ks + khalf;
        bf16x8 bu0 = __builtin_bit_cast(bf16x8, U[mrow0 * 32 + (c0 ^ (mrow0 & 7))]);
        bf16x8 bu1 = __builtin_bit_cast(bf16x8, U[mrow1 * 32 + (c0 ^ (mrow1 & 7))]);
        bf16x8 af0, af1;
        if (ks < 8) { af0 = w2c[0][ks]; af1 = w2c[1][ks]; }
        else {
          af0 = __builtin_bit_cast(bf16x8, w2f[(ot0 * 16 + ks) * 64 + l]);
          af1 = __builtin_bit_cast(bf16x8, w2f[((ot0 + 1) * 16 + ks) * 64 + l]);
        }
        acc[0][0] = MFMA32(af0, bu0, acc[0][0]);
        acc[0][1] = MFMA32(af1, bu0, acc[0][1]);
        acc[1][0] = MFMA32(af0, bu1, acc[1][0]);
        acc[1][1] = MFMA32(af1, bu1, acc[1][1]);
      }
    }
    __syncthreads();
    // ---- relu + bf16 pack + swizzled writeback (C layout: col=m, row=o) ----
#pragma unroll
    for (int mt = 0; mt < 2; ++mt) {
      int row = mt ? mrow1 : mrow0;
#pragma unroll
      for (int t2 = 0; t2 < 2; ++t2) {
        int ot = ot0 + t2;
#pragma unroll
        for (int q = 0; q < 4; ++q) {
          bf16x4 h;
          h.x = (__bf16)fmaxf(acc[mt][t2][4 * q + 0], 0.0f);
          h.y = (__bf16)fmaxf(acc[mt][t2][4 * q + 1], 0.0f);
          h.z = (__bf16)fmaxf(acc[mt][t2][4 * q + 2], 0.0f);
          h.w = (__bf16)fmaxf(acc[mt][t2][4 * q + 3], 0.0f);
          int co = ot * 4 + q;
          int coff = row * 32 + (co ^ (row & 7));
          *(uint2*)((char*)(U + coff) + khalf * 8) = __builtin_bit_cast(uint2, h);
        }
      }
    }
    __syncthreads();
  }

  // ---- dump final shifted state (verbatim swizzled layout) to workspace ----
  int4* stg = (int4*)(ws + STATE_OFF) + (phase * 512 + tile) * 2048;
#pragma unroll
  for (int i = 0; i < 8; ++i) stg[i * 256 + tid] = U[i * 256 + tid];
}

__global__ __launch_bounds__(256, 2)
void final_kernel(const float* __restrict__ x, const unsigned short* __restrict__ ws,
                  float* __restrict__ out) {
  __shared__ int4 S[2][64 * 32];  // sup / sdown tiles, swizzled chunk layout
  __shared__ int4 xw[64];         // rows j0..j0+63 (always in-range)
  __shared__ int4 zc;

  const int tid = threadIdx.x;
  const int l = tid & 63;
  const int w = tid >> 6;
  const int lane31 = l & 31;
  const int khalf = l >> 5;
  const int tile = blockIdx.x;
  const int b = tile >> 5;
  const int j0 = (tile & 31) * 64;

  const int4* w4f = (const int4*)(ws + 65536);
  const int4* w3xg = (const int4*)(ws + 135168);
  const int4* stg = (const int4*)(ws + STATE_OFF);

  if (tid == 0) zc = make_int4(0, 0, 0, 0);
  if (tid < 64) {
    int j = j0 + tid;
    const float* xb = x + (b * 4) * 2048 + j;
    unsigned short h0 = f2bf(xb[0]);
    unsigned short h1 = f2bf(xb[2048]);
    unsigned short h2 = f2bf(xb[4096]);
    unsigned short h3 = f2bf(xb[6144]);
    xw[tid] = make_int4((int)(h0 | ((unsigned int)h1 << 16)),
                        (int)(h2 | ((unsigned int)h3 << 16)),
                        0x00003f80, 0);
  }
#pragma unroll
  for (int i = 0; i < 8; ++i) {
    S[0][i * 256 + tid] = stg[tile * 2048 + i * 256 + tid];
    S[1][i * 256 + tid] = stg[(512 + tile) * 2048 + i * 256 + tid];
  }
  __syncthreads();

  const int ot0 = w * 2;
  const int mrow0 = lane31;
  const int mrow1 = 32 + lane31;

  f32x16 acc[2][2] = {};
  bf16x8 w3x0 = __builtin_bit_cast(bf16x8, w3xg[ot0 * 64 + l]);
  bf16x8 w3x1 = __builtin_bit_cast(bf16x8, w3xg[(ot0 + 1) * 64 + l]);
#pragma unroll
  for (int mt = 0; mt < 2; ++mt) {
    int m = mt ? mrow1 : mrow0;
    const int4* p = (l < 32) ? (xw + m) : (&zc);
    bf16x8 bx = __builtin_bit_cast(bf16x8, *p);
    acc[mt][0] = MFMA32(w3x0, bx, acc[mt][0]);
    acc[mt][1] = MFMA32(w3x1, bx, acc[mt][1]);
  }
#pragma unroll 1
  for (int ph = 0; ph < 2; ++ph) {
    const int4* Sp = S[ph];
#pragma unroll
    for (int ks = 0; ks < 16; ++ks) {
      int c0 = 2 * ks + khalf;
      bf16x8 bu0 = __builtin_bit_cast(bf16x8, Sp[mrow0 * 32 + (c0 ^ (mrow0 & 7))]);
      bf16x8 bu1 = __builtin_bit_cast(bf16x8, Sp[mrow1 * 32 + (c0 ^ (mrow1 & 7))]);
      bf16x8 af0 = __builtin_bit_cast(bf16x8, w4f[(ot0 * 16 + ks) * 64 + l]);
      bf16x8 af1 = __builtin_bit_cast(bf16x8, w4f[((ot0 + 1) * 16 + ks) * 64 + l]);
      acc[0][0] = MFMA32(af0, bu0, acc[0][0]);
      acc[0][1] = MFMA32(af1, bu0, acc[0][1]);
      acc[1][0] = MFMA32(af0, bu1, acc[1][0]);
      acc[1][1] = MFMA32(af1, bu1, acc[1][1]);
    }
  }
#pragma unroll
  for (int mt = 0; mt < 2; ++mt) {
    int m = mt ? mrow1 : mrow0;
    int pbase = (b * 2048 + j0 + m) * 256;
#pragma unroll
    for (int t2 = 0; t2 < 2; ++t2) {
#pragma unroll
      for (int q = 0; q < 4; ++q) {
        int ob = (ot0 + t2) * 32 + 8 * q + 4 * khalf;
        float4 v;
        v.x = fmaxf(acc[mt][t2][4 * q + 0], 0.0f);
        v.y = fmaxf(acc[mt][t2][4 * q + 1], 0.0f);
        v.z = fmaxf(acc[mt][t2][4 * q + 2], 0.0f);
        v.w = fmaxf(acc[mt][t2][4 * q + 3], 0.0f);
        *(float4*)(out + pbase + ob) = v;
      }
    }
  }
}

extern "C" void kernel_launch(void* const* d_in, const int* in_sizes, int n_in,
                              void* d_out, int out_size, void* d_ws, size_t ws_size,
                              hipStream_t stream) {
  const float* x  = (const float*)d_in[0];
  const float* W1 = (const float*)d_in[1];
  const float* b1 = (const float*)d_in[2];
  const float* W2 = (const float*)d_in[3];
  const float* b2 = (const float*)d_in[4];
  const float* W3 = (const float*)d_in[5];
  const float* b3 = (const float*)d_in[6];
  const float* W4 = (const float*)d_in[7];
  const float* b4 = (const float*)d_in[8];
  unsigned short* ws = (unsigned short*)d_ws;

  prep_kernel<<<544, 256, 0, stream>>>(W1, b1, W2, b2, W3, b3, W4, b4, ws);
  chain_kernel<<<1024, 256, 0, stream>>>(x, ws);
  final_kernel<<<512, 256, 0, stream>>>(x, ws, (float*)d_out);
}

// Round 4
// 154.416 us; speedup vs baseline: 1.7727x; 1.6479x over previous
//
#include <hip/hip_runtime.h>

// BahdanauAttention_16518444220431 — diagonal-DP recurrence on MI355X (gfx950).
// R4: R3 structure (1024 parallel chain blocks, 8 serial steps, one 32KB U
// buffer, state round-trip via d_ws) with launch_bounds REVERTED to (256,2).
// LESSON (R2,R3): bounds tighter than (256,2) cap VGPR at 64 and spill the
// 64-AGPR accumulator (FETCH 10MB -> 376MB). (256,2) gives 128 VGPR, no
// spill; HW still co-schedules 4 blocks/CU (128 VGPR -> 4 waves/SIMD, 34KB
// LDS -> 4 blocks/CU).

typedef __bf16 bf16x8 __attribute__((ext_vector_type(8)));
typedef __bf16 bf16x4 __attribute__((ext_vector_type(4)));
typedef float f32x16 __attribute__((ext_vector_type(16)));

#define MFMA32(a, b, c) __builtin_amdgcn_mfma_f32_32x32x16_bf16(a, b, c, 0, 0, 0)

__device__ __forceinline__ unsigned short f2bf(float f) {
  unsigned int u = __builtin_bit_cast(unsigned int, f);
  u += 0x7fffu + ((u >> 16) & 1u);
  return (unsigned short)(u >> 16);
}

// ws layout (bf16 elements):
//   [0,65536)        W2 fragments: ((ot*16+ks)*64+lane)*8+j ; o=ot*32+(lane&31), k=ks*16+(lane>>5)*8+j
//   [65536,131072)   W4 fragments, same permutation
//   [131072,135168)  W1-extra frags: lanes<32: j<4 -> W1[o][j], j==4 -> b1[o]+b2[o], else 0
//   [135168,139264)  W3-extra frags: j==4 -> b3[o]+2*b4[o]
//   [139264, +2*512*32768)  chain states: [chain][tile512][2048 int4] (swizzled chunk layout)
#define STATE_OFF 139264

__global__ void prep_kernel(const float* __restrict__ W1, const float* __restrict__ b1,
                            const float* __restrict__ W2, const float* __restrict__ b2,
                            const float* __restrict__ W3, const float* __restrict__ b3,
                            const float* __restrict__ W4, const float* __restrict__ b4,
                            unsigned short* __restrict__ ws) {
  int idx = blockIdx.x * 256 + threadIdx.x;
  if (idx >= 139264) return;
  float v = 0.0f;
  if (idx < 131072) {
    const float* W = (idx < 65536) ? W2 : W4;
    int i = idx & 65535;
    int j = i & 7, f = i >> 3;
    int lane = f & 63, slot = f >> 6;
    int ks = slot & 15, ot = slot >> 4;
    int o = ot * 32 + (lane & 31);
    int k = ks * 16 + (lane >> 5) * 8 + j;
    v = W[o * 256 + k];
  } else {
    int i = idx - 131072;
    bool first = (i < 4096);
    int ii = i & 4095;
    int j = ii & 7, f = ii >> 3;
    int lane = f & 63, ot = f >> 6;
    int o = ot * 32 + (lane & 31);
    if (lane < 32) {
      if (j < 4) v = first ? W1[o * 4 + j] : W3[o * 4 + j];
      else if (j == 4) v = first ? (b1[o] + b2[o]) : (b3[o] + 2.0f * b4[o]);
    }
  }
  ws[idx] = f2bf(v);
}

__global__ __launch_bounds__(256, 2)
void chain_kernel(const float* __restrict__ x, unsigned short* __restrict__ ws) {
  // U: 64 rows x 32 16B-chunks (256 bf16/row), chunk XOR-swizzled by (row&7)
  __shared__ int4 U[64 * 32];
  __shared__ int4 xw[80];   // [x0,x1,x2,x3,1,0,0,0] bf16 chunks for rows j0-8 .. j0+71
  __shared__ int4 zc;

  const int tid = threadIdx.x;
  const int l = tid & 63;
  const int w = tid >> 6;
  const int lane31 = l & 31;
  const int khalf = l >> 5;
  const int phase = blockIdx.x >> 9;           // 0 = up, 1 = down
  const int tile = blockIdx.x & 511;
  const int b = tile >> 5;
  const int j0 = (tile & 31) * 64;

  const int4* w2f = (const int4*)ws;
  const int4* w1xg = (const int4*)(ws + 131072);

  if (tid == 0) zc = make_int4(0, 0, 0, 0);
  if (tid < 80) {
    int j = j0 - 8 + tid;
    int4 c = make_int4(0, 0, 0, 0);
    if (j >= 0 && j < 2048) {
      const float* xb = x + (b * 4) * 2048 + j;
      unsigned short h0 = f2bf(xb[0]);
      unsigned short h1 = f2bf(xb[2048]);
      unsigned short h2 = f2bf(xb[4096]);
      unsigned short h3 = f2bf(xb[6144]);
      c = make_int4((int)(h0 | ((unsigned int)h1 << 16)),
                    (int)(h2 | ((unsigned int)h3 << 16)),
                    0x00003f80, 0);  // chunk[4] = bf16(1.0) multiplies the bias row
    }
    xw[tid] = c;
  }

  const int ot0 = w * 2;
  bf16x8 w2c[2][8];
  bf16x8 w1x[2];
#pragma unroll
  for (int t2 = 0; t2 < 2; ++t2) {
    w1x[t2] = __builtin_bit_cast(bf16x8, w1xg[(ot0 + t2) * 64 + l]);
#pragma unroll
    for (int ks = 0; ks < 8; ++ks)
      w2c[t2][ks] = __builtin_bit_cast(bf16x8, w2f[((ot0 + t2) * 16 + ks) * 64 + l]);
  }
  __syncthreads();

  const int mrow0 = lane31;
  const int mrow1 = 32 + lane31;

#pragma unroll 1
  for (int t = 1; t <= 8; ++t) {
    f32x16 acc[2][2] = {};
    // ---- extra K=16 step: adds a[pos] + bias (zero chunk beyond seq edges) ----
#pragma unroll
    for (int mt = 0; mt < 2; ++mt) {
      int m = mt ? mrow1 : mrow0;
      int widx = (phase == 0) ? (m + t - 1) : (m + 17 - t);
      const int4* p = (l < 32) ? (xw + widx) : (&zc);
      bf16x8 bx = __builtin_bit_cast(bf16x8, *p);
      acc[mt][0] = MFMA32(w1x[0], bx, acc[mt][0]);
      acc[mt][1] = MFMA32(w1x[1], bx, acc[mt][1]);
    }
    // ---- main GEMM over previous state (skip at t=1: state is zero) ----
    if (t > 1) {
#pragma unroll
      for (int ks = 0; ks < 16; ++ks) {
        int c0 = 2 * ks + khalf;
        bf16x8 bu0 = __builtin_bit_cast(bf16x8, U[mrow0 * 32 + (c0 ^ (mrow0 & 7))]);
        bf16x8 bu1 = __builtin_bit_cast(bf16x8, U[mrow1 * 32 + (c0 ^ (mrow1 & 7))]);
        bf16x8 af0, af1;
        if (ks < 8) { af0 = w2c[0][ks]; af1 = w2c[1][ks]; }
        else {
          af0 = __builtin_bit_cast(bf16x8, w2f[(ot0 * 16 + ks) * 64 + l]);
          af1 = __builtin_bit_cast(bf16x8, w2f[((ot0 + 1) * 16 + ks) * 64 + l]);
        }
        acc[0][0] = MFMA32(af0, bu0, acc[0][0]);
        acc[0][1] = MFMA32(af1, bu0, acc[0][1]);
        acc[1][0] = MFMA32(af0, bu1, acc[1][0]);
        acc[1][1] = MFMA32(af1, bu1, acc[1][1]);
      }
    }
    __syncthreads();
    // ---- relu + bf16 pack + swizzled writeback (C layout: col=m, row=o) ----
#pragma unroll
    for (int mt = 0; mt < 2; ++mt) {
      int row = mt ? mrow1 : mrow0;
#pragma unroll
      for (int t2 = 0; t2 < 2; ++t2) {
        int ot = ot0 + t2;
#pragma unroll
        for (int q = 0; q < 4; ++q) {
          bf16x4 h;
          h.x = (__bf16)fmaxf(acc[mt][t2][4 * q + 0], 0.0f);
          h.y = (__bf16)fmaxf(acc[mt][t2][4 * q + 1], 0.0f);
          h.z = (__bf16)fmaxf(acc[mt][t2][4 * q + 2], 0.0f);
          h.w = (__bf16)fmaxf(acc[mt][t2][4 * q + 3], 0.0f);
          int co = ot * 4 + q;
          int coff = row * 32 + (co ^ (row & 7));
          *(uint2*)((char*)(U + coff) + khalf * 8) = __builtin_bit_cast(uint2, h);
        }
      }
    }
    __syncthreads();
  }

  // ---- dump final shifted state (verbatim swizzled layout) to workspace ----
  int4* stg = (int4*)(ws + STATE_OFF) + (phase * 512 + tile) * 2048;
#pragma unroll
  for (int i = 0; i < 8; ++i) stg[i * 256 + tid] = U[i * 256 + tid];
}

__global__ __launch_bounds__(256, 2)
void final_kernel(const float* __restrict__ x, const unsigned short* __restrict__ ws,
                  float* __restrict__ out) {
  __shared__ int4 S[2][64 * 32];  // sup / sdown tiles, swizzled chunk layout
  __shared__ int4 xw[64];         // rows j0..j0+63 (always in-range)
  __shared__ int4 zc;

  const int tid = threadIdx.x;
  const int l = tid & 63;
  const int w = tid >> 6;
  const int lane31 = l & 31;
  const int khalf = l >> 5;
  const int tile = blockIdx.x;
  const int b = tile >> 5;
  const int j0 = (tile & 31) * 64;

  const int4* w4f = (const int4*)(ws + 65536);
  const int4* w3xg = (const int4*)(ws + 135168);
  const int4* stg = (const int4*)(ws + STATE_OFF);

  if (tid == 0) zc = make_int4(0, 0, 0, 0);
  if (tid < 64) {
    int j = j0 + tid;
    const float* xb = x + (b * 4) * 2048 + j;
    unsigned short h0 = f2bf(xb[0]);
    unsigned short h1 = f2bf(xb[2048]);
    unsigned short h2 = f2bf(xb[4096]);
    unsigned short h3 = f2bf(xb[6144]);
    xw[tid] = make_int4((int)(h0 | ((unsigned int)h1 << 16)),
                        (int)(h2 | ((unsigned int)h3 << 16)),
                        0x00003f80, 0);
  }
#pragma unroll
  for (int i = 0; i < 8; ++i) {
    S[0][i * 256 + tid] = stg[tile * 2048 + i * 256 + tid];
    S[1][i * 256 + tid] = stg[(512 + tile) * 2048 + i * 256 + tid];
  }
  __syncthreads();

  const int ot0 = w * 2;
  const int mrow0 = lane31;
  const int mrow1 = 32 + lane31;

  f32x16 acc[2][2] = {};
  bf16x8 w3x0 = __builtin_bit_cast(bf16x8, w3xg[ot0 * 64 + l]);
  bf16x8 w3x1 = __builtin_bit_cast(bf16x8, w3xg[(ot0 + 1) * 64 + l]);
#pragma unroll
  for (int mt = 0; mt < 2; ++mt) {
    int m = mt ? mrow1 : mrow0;
    const int4* p = (l < 32) ? (xw + m) : (&zc);
    bf16x8 bx = __builtin_bit_cast(bf16x8, *p);
    acc[mt][0] = MFMA32(w3x0, bx, acc[mt][0]);
    acc[mt][1] = MFMA32(w3x1, bx, acc[mt][1]);
  }
#pragma unroll 1
  for (int ph = 0; ph < 2; ++ph) {
    const int4* Sp = S[ph];
#pragma unroll
    for (int ks = 0; ks < 16; ++ks) {
      int c0 = 2 * ks + khalf;
      bf16x8 bu0 = __builtin_bit_cast(bf16x8, Sp[mrow0 * 32 + (c0 ^ (mrow0 & 7))]);
      bf16x8 bu1 = __builtin_bit_cast(bf16x8, Sp[mrow1 * 32 + (c0 ^ (mrow1 & 7))]);
      bf16x8 af0 = __builtin_bit_cast(bf16x8, w4f[(ot0 * 16 + ks) * 64 + l]);
      bf16x8 af1 = __builtin_bit_cast(bf16x8, w4f[((ot0 + 1) * 16 + ks) * 64 + l]);
      acc[0][0] = MFMA32(af0, bu0, acc[0][0]);
      acc[0][1] = MFMA32(af1, bu0, acc[0][1]);
      acc[1][0] = MFMA32(af0, bu1, acc[1][0]);
      acc[1][1] = MFMA32(af1, bu1, acc[1][1]);
    }
  }
#pragma unroll
  for (int mt = 0; mt < 2; ++mt) {
    int m = mt ? mrow1 : mrow0;
    int pbase = (b * 2048 + j0 + m) * 256;
#pragma unroll
    for (int t2 = 0; t2 < 2; ++t2) {
#pragma unroll
      for (int q = 0; q < 4; ++q) {
        int ob = (ot0 + t2) * 32 + 8 * q + 4 * khalf;
        float4 v;
        v.x = fmaxf(acc[mt][t2][4 * q + 0], 0.0f);
        v.y = fmaxf(acc[mt][t2][4 * q + 1], 0.0f);
        v.z = fmaxf(acc[mt][t2][4 * q + 2], 0.0f);
        v.w = fmaxf(acc[mt][t2][4 * q + 3], 0.0f);
        *(float4*)(out + pbase + ob) = v;
      }
    }
  }
}

extern "C" void kernel_launch(void* const* d_in, const int* in_sizes, int n_in,
                              void* d_out, int out_size, void* d_ws, size_t ws_size,
                              hipStream_t stream) {
  const float* x  = (const float*)d_in[0];
  const float* W1 = (const float*)d_in[1];
  const float* b1 = (const float*)d_in[2];
  const float* W2 = (const float*)d_in[3];
  const float* b2 = (const float*)d_in[4];
  const float* W3 = (const float*)d_in[5];
  const float* b3 = (const float*)d_in[6];
  const float* W4 = (const float*)d_in[7];
  const float* b4 = (const float*)d_in[8];
  unsigned short* ws = (unsigned short*)d_ws;

  prep_kernel<<<544, 256, 0, stream>>>(W1, b1, W2, b2, W3, b3, W4, b4, ws);
  chain_kernel<<<1024, 256, 0, stream>>>(x, ws);
  final_kernel<<<512, 256, 0, stream>>>(x, ws, (float*)d_out);
}